// Round 10
// baseline (589.372 us; speedup 1.0000x reference)
//
#include <hip/hip_runtime.h>
#include <hip/hip_cooperative_groups.h>

// NonLocalBlock: B=4, C=256, Ci=128, H=W=64, N=4096.
// R19: single cooperative mono-kernel (grid 256 x 512, 1 block/CU, 5
// grid.sync()s). R16/R18 post-mortem: dispatch gap+launch ~5us each
// (R16 fold: -12.6 for 2), in-kernel opts plateaued; 6 dispatches -> 1
// removes 5 gaps (~25us) at the cost of 5 grid syncs (~8us). Phase bodies
// are verbatim R16/R18 kernels re-indexed: P0 init (1cvt/thr), P1 proj
// (2 units/blk via sub=t>>8), P2 cols (2par x 4seq units/blk), P3 attn
// (verbatim: counted-vmcnt 3-buffer, in-reg softmax), P4 wz (R18 512x32n,
// 2/blk), P5 final (2x4 units/blk). __threadfence before each sync for
// cross-XCD visibility. LDS 100KB static (attn layout; other phases alias).

namespace cg = cooperative_groups;

#define B_  4
#define C_  256
#define CI  128
#define N_  4096
#define NB  (B_*N_)     // 16384
#define ISPLIT 16
#define MB_ (1u<<20)
#define LOG2E 1.442695041f

typedef _Float16 f16;
typedef f16   f16x8 __attribute__((ext_vector_type(8)));
typedef f16   f16x4 __attribute__((ext_vector_type(4)));
typedef float f32x4 __attribute__((ext_vector_type(4)));
typedef float f32x16 __attribute__((ext_vector_type(16)));
typedef unsigned u32x2 __attribute__((ext_vector_type(2)));
typedef unsigned u32x4v __attribute__((ext_vector_type(4)));

#define MFMA(a,b,c)   __builtin_amdgcn_mfma_f32_16x16x32_f16(a,b,c,0,0,0)
#define MFMA32(a,b,c) __builtin_amdgcn_mfma_f32_32x32x16_f16(a,b,c,0,0,0)

// async global->LDS, 16B per lane; LDS dest = wave-uniform base + lane*16
#define GLD16(g, lp) __builtin_amdgcn_global_load_lds( \
    (const __attribute__((address_space(1))) void*)(g), \
    (__attribute__((address_space(3))) void*)(lp), 16, 0, 0)

// ---- workspace byte offsets (~29.3 MB) ----
#define OFF_THETA  0                 // f16 [B][N][CI]  4 MB (pre-scaled by log2e)
#define OFF_PHI    (4u*MB_)          // f16 [B][N][CI]  4 MB
#define OFF_G      (8u*MB_)          // f16 [B][CI][N]  4 MB
#define OFF_YP     (12u*MB_)         // f16 [4][B][N][CI]  16 MB (j-quarter partials)
#define OFF_WY     0                 // f16 [B][C][N] 8 MB — overlays theta+phi (dead by wz)
#define OFF_PS     (28u*MB_)                  // f32 [ISPLIT][NB]  1 MB
#define OFF_PSUM   OFF_PS                     // f32 [256][2][512] 1 MB — overlays ps (dead after attn)
#define OFF_WCVT   (OFF_PS + ISPLIT*NB*4)     // f16 weights g,t,p,z  256 KB
#define PSZ ((size_t)B_*N_*CI)

__global__ __launch_bounds__(512, 2) void k_mono(
        const float* __restrict__ x,
        const float* __restrict__ gw, const float* __restrict__ gb,
        const float* __restrict__ tw, const float* __restrict__ tbv,
        const float* __restrict__ pw, const float* __restrict__ pb,
        const float* __restrict__ zw, const float* __restrict__ zb,
        const float* __restrict__ gamma, const float* __restrict__ beta,
        float* __restrict__ out, char* __restrict__ ws) {
    cg::grid_group grid = cg::this_grid();
    __shared__ __align__(16) char smem[102400];

    f16* thetaT = (f16*)(ws + OFF_THETA);
    f16* phiT   = (f16*)(ws + OFF_PHI);
    f16* gC     = (f16*)(ws + OFF_G);
    f16* yP     = (f16*)(ws + OFF_YP);
    f16* wy     = (f16*)(ws + OFF_WY);
    f16* wcvt   = (f16*)(ws + OFF_WCVT);
    float* ps   = (float*)(ws + OFF_PS);
    float* psum = (float*)(ws + OFF_PSUM);

    int t = threadIdx.x;
    int blk = blockIdx.x;                 // 0..255
    int sub = t >> 8, tt = t & 255;

    // ================= P0: weight cvt f32->f16 (1 elem/thread) =============
    {
        int i = blk * 512 + t;            // 0..131071
        const float* s;
        int which = i >> 15;
        if (which == 0) s = gw; else if (which == 1) s = tw;
        else if (which == 2) s = pw; else s = zw;
        wcvt[i] = (f16)s[i & 32767];
    }
    __threadfence();
    grid.sync();

    // ================= P1: proj — 2 units/block (sub) ======================
    {
        f16* xT = (f16*)smem + (size_t)sub * (32 * 264);   // [n][c] stride 264
        int vid = blk * 2 + sub;          // 0..511
        int bb = vid >> 7;
        int n0 = (vid & 127) * 32;

        const float* xb = x + (size_t)bb * C_ * N_;
        for (int rep = 0; rep < 8; rep++) {
            int lin = rep * 256 + tt;
            int c = lin >> 3, np = (lin & 7) * 4;
            float4 v = *reinterpret_cast<const float4*>(xb + c * N_ + n0 + np);
            xT[(np + 0) * 264 + c] = (f16)v.x;
            xT[(np + 1) * 264 + c] = (f16)v.y;
            xT[(np + 2) * 264 + c] = (f16)v.z;
            xT[(np + 3) * 264 + c] = (f16)v.w;
        }
        __syncthreads();

        int w4 = tt >> 6, l16 = tt & 15, q = (tt & 63) >> 4;
        int ci0 = w4 * 32;
        for (int proj = 0; proj < 3; proj++) {
            const f16* W0 = wcvt + proj * 32768;   // [128][256] f16 row-major
            f32x4 acc[2][2] = {};
            for (int kk = 0; kk < 8; kk++) {
                f16x8 a0 = *reinterpret_cast<const f16x8*>(W0 + (ci0 + l16) * 256 + kk * 32 + q * 8);
                f16x8 a1 = *reinterpret_cast<const f16x8*>(W0 + (ci0 + 16 + l16) * 256 + kk * 32 + q * 8);
#pragma unroll
                for (int nt = 0; nt < 2; nt++) {
                    f16x8 bv = *reinterpret_cast<const f16x8*>(&xT[(nt * 16 + l16) * 264 + kk * 32 + q * 8]);
                    acc[0][nt] = MFMA(a0, bv, acc[0][nt]);
                    acc[1][nt] = MFMA(a1, bv, acc[1][nt]);
                }
            }
            const float* bias = (proj == 0) ? gb : (proj == 1) ? tbv : pb;
            float scl = (proj == 1) ? LOG2E : 1.0f;   // fold ln2 into theta
#pragma unroll
            for (int a = 0; a < 2; a++) {
#pragma unroll
                for (int nt = 0; nt < 2; nt++) {
                    int n = n0 + nt * 16 + l16;
                    int cib = ci0 + a * 16 + q * 4;
                    if (proj == 0) {
#pragma unroll
                        for (int r = 0; r < 4; r++)
                            gC[((size_t)bb * CI + cib + r) * N_ + n] = (f16)(acc[a][nt][r] + bias[cib + r]);
                    } else {
                        f16x4 v4;
#pragma unroll
                        for (int r = 0; r < 4; r++)
                            v4[r] = (f16)((acc[a][nt][r] + bias[cib + r]) * scl);
                        f16* dst = (proj == 1 ? thetaT : phiT) + ((size_t)bb * N_ + n) * CI + cib;
                        *reinterpret_cast<f16x4*>(dst) = v4;
                    }
                }
            }
        }
    }
    __threadfence();
    grid.sync();

    // ================= P2: cols — 2 parallel x 4 sequential units ==========
    {
        f16* thS = (f16*)smem + (size_t)sub * 16384;   // [2][8192] per sub
        int wl = tt >> 6, l = tt & 63, l31 = l & 31, hi = l >> 5;
        for (int rep = 0; rep < 4; rep++) {
            int unit = blk * 8 + sub * 4 + rep;        // 0..2047
            int isp = unit & 15, jb = (unit >> 4) & 31, bb = unit >> 9;
            int jw = jb * 128 + wl * 32 + l31;

            f16x8 pf[8];
            const f16* pb2 = phiT + ((size_t)bb * N_ + jw) * CI + hi * 8;
#pragma unroll
            for (int kk = 0; kk < 8; kk++)
                pf[kk] = *reinterpret_cast<const f16x8*>(pb2 + kk * 16);

            const f16* thB = thetaT + ((size_t)bb * N_ + isp * 256) * CI;
            auto stage = [&](int bf, int it0) {
#pragma unroll
                for (int r = 0; r < 4; r++) {
                    int p = r * 256 + wl * 64 + l;
                    int pi = p >> 4, pu = (p & 15) ^ (pi & 15);
                    const char* ga = (const char*)(thB + (size_t)(it0 + pi) * CI) + pu * 16;
                    GLD16(ga, thS + bf * 8192 + (r * 256 + wl * 64) * 8);
                }
            };

            float s = 0.f;
            stage(0, 0);
            __syncthreads();
            for (int it = 0; it < 4; it++) {
                int bf = it & 1;
                if (it + 1 < 4) stage(bf ^ 1, (it + 1) * 64);
#pragma unroll
                for (int it2 = 0; it2 < 2; it2++) {
                    f16x8 av[8];
#pragma unroll
                    for (int kk = 0; kk < 8; kk++)
                        av[kk] = *reinterpret_cast<const f16x8*>(
                            thS + bf * 8192 + (it2 * 32 + l31) * 128 + (((kk * 2 + hi) ^ (l31 & 15)) * 8));
                    f32x16 f = {};
                    __builtin_amdgcn_s_setprio(1);
#pragma unroll
                    for (int kk = 0; kk < 8; kk++)
                        f = MFMA32(av[kk], pf[kk], f);
                    __builtin_amdgcn_s_setprio(0);
#pragma unroll
                    for (int r = 0; r < 16; r++)
                        s += __builtin_amdgcn_exp2f(f[r]);
                }
                __syncthreads();
            }
            s += __shfl_xor(s, 32);
            if (hi == 0)
                ps[isp * NB + bb * N_ + jw] = s;
        }
    }
    __threadfence();
    grid.sync();

    // ================= P3: attn (verbatim R16) =============================
    {
        f16 (*phiS)[64 * 128] = (f16(*)[64 * 128])smem;            // 3 x 16 KB [j][ci]
        f16 (*gS)[128 * 64]   = (f16(*)[128 * 64])(smem + 49152);  // 3 x 16 KB [ci][j]
        float* mdL = (float*)(smem + 98304);                       // [1024] -log2 D

        int jq = blk & 3;
        int ib = blk >> 2;             // 0..63
        int bb = ib >> 4;
        int i0 = (ib & 15) * 256;
        int w = t >> 6, l = t & 63;
        int l31 = l & 31, hi = l >> 5;
        int js = w >> 2, iw = w & 3;
        int jbase = jq * 1024;

        // fold of colmerge: mdL slice from ps (before staging issues)
        {
            const float* pp = ps + bb * N_ + jbase;
            float s0 = 0.f, s1 = 0.f;
#pragma unroll
            for (int isp = 0; isp < ISPLIT; isp++) {
                s0 += pp[isp * NB + t];
                s1 += pp[isp * NB + t + 512];
            }
            mdL[t]       = -__log2f(s0);
            mdL[t + 512] = -__log2f(s1);
        }

        // theta B-fragments, 2 i-sets of 32: B[n=i][k]; lane n=l31, k=hi*8+e
        f16x8 ta[2][8];
#pragma unroll
        for (int is = 0; is < 2; is++) {
            const f16* tb = thetaT + ((size_t)bb * N_ + i0 + iw * 64 + is * 32 + l31) * CI + hi * 8;
#pragma unroll
            for (int kk = 0; kk < 8; kk++)
                ta[is][kk] = *reinterpret_cast<const f16x8*>(tb + kk * 16);
        }

        const f16* phiB = phiT + (size_t)bb * N_ * CI;
        const f16* gB   = gC   + (size_t)bb * CI * N_;

        auto stage = [&](int bf, int j0g) {
#pragma unroll
            for (int r = 0; r < 2; r++) {
                int p = r * 512 + t;
                int ub = (r * 512 + w * 64) * 8;      // wave-uniform LDS base (f16)
                int pj = p >> 4, pu = (p & 15) ^ (pj & 15);
                const char* ga = (const char*)(phiB + (size_t)(j0g + pj) * CI) + pu * 16;
                GLD16(ga, &phiS[bf][ub]);
                int pc = p >> 3, pu2 = (p & 7) ^ (pc & 7);
                const char* ga2 = (const char*)(gB + (size_t)pc * N_ + j0g) + pu2 * 16;
                GLD16(ga2, &gS[bf][ub]);
            }
        };

        stage(0, jbase);
        stage(1, jbase + 64);
        asm volatile("s_waitcnt vmcnt(4) lgkmcnt(0)" ::: "memory");
        __builtin_amdgcn_s_barrier();

        f32x16 yacc[2][4] = {};          // [iset][cs]: y[i 32][ci = cs*32+l31]
        for (int jt = 0; jt < 16; jt++) {
            int bf = jt % 3;
            if (jt + 2 < 16) stage((jt + 2) % 3, jbase + (jt + 2) * 64);

            f32x16 facc[2];
#pragma unroll
            for (int c = 0; c < 4; c++) {
                f32x4 v = *reinterpret_cast<const f32x4*>(
                    &mdL[jt * 64 + js * 32 + c * 8 + hi * 4]);
                facc[0][c * 4 + 0] = v[0]; facc[0][c * 4 + 1] = v[1];
                facc[0][c * 4 + 2] = v[2]; facc[0][c * 4 + 3] = v[3];
                facc[1][c * 4 + 0] = v[0]; facc[1][c * 4 + 1] = v[1];
                facc[1][c * 4 + 2] = v[2]; facc[1][c * 4 + 3] = v[3];
            }

            __builtin_amdgcn_s_setprio(1);
#pragma unroll
            for (int kk = 0; kk < 8; kk++) {
                f16x8 pv = *reinterpret_cast<const f16x8*>(
                    &phiS[bf][(js * 32 + l31) * 128 + (((kk * 2 + hi) ^ (l31 & 15)) * 8)]);
                facc[0] = MFMA32(pv, ta[0][kk], facc[0]);
                facc[1] = MFMA32(pv, ta[1][kk], facc[1]);
            }
            __builtin_amdgcn_s_setprio(0);

#pragma unroll
            for (int ch = 0; ch < 2; ch++) {
                f16x8 wfr[2];
#pragma unroll
                for (int is = 0; is < 2; is++) {
                    float e0 = __builtin_amdgcn_exp2f(facc[is][ch * 8 + 0]);
                    float e1 = __builtin_amdgcn_exp2f(facc[is][ch * 8 + 1]);
                    float e2 = __builtin_amdgcn_exp2f(facc[is][ch * 8 + 2]);
                    float e3 = __builtin_amdgcn_exp2f(facc[is][ch * 8 + 3]);
                    float e4 = __builtin_amdgcn_exp2f(facc[is][ch * 8 + 4]);
                    float e5 = __builtin_amdgcn_exp2f(facc[is][ch * 8 + 5]);
                    float e6 = __builtin_amdgcn_exp2f(facc[is][ch * 8 + 6]);
                    float e7 = __builtin_amdgcn_exp2f(facc[is][ch * 8 + 7]);
                    unsigned p01 = __builtin_bit_cast(unsigned, __builtin_amdgcn_cvt_pkrtz(e0, e1));
                    unsigned p23 = __builtin_bit_cast(unsigned, __builtin_amdgcn_cvt_pkrtz(e2, e3));
                    unsigned p45 = __builtin_bit_cast(unsigned, __builtin_amdgcn_cvt_pkrtz(e4, e5));
                    unsigned p67 = __builtin_bit_cast(unsigned, __builtin_amdgcn_cvt_pkrtz(e6, e7));
                    u32x2 s0 = __builtin_amdgcn_permlane32_swap(p01, p45, false, false);
                    u32x2 s1 = __builtin_amdgcn_permlane32_swap(p23, p67, false, false);
                    u32x4v wu = {s0[0], s1[0], s0[1], s1[1]};
                    wfr[is] = __builtin_bit_cast(f16x8, wu);   // A[m=i=l31][k=hi*8+e]
                }
                int jc = js * 2 + ch;                          // 16-j chunk index
                __builtin_amdgcn_s_setprio(1);
#pragma unroll
                for (int cs = 0; cs < 4; cs++) {
                    f16x8 gv = *reinterpret_cast<const f16x8*>(
                        &gS[bf][(cs * 32 + l31) * 64 + (((jc * 2 + hi) ^ (l31 & 7)) * 8)]);
                    yacc[0][cs] = MFMA32(wfr[0], gv, yacc[0][cs]);
                    yacc[1][cs] = MFMA32(wfr[1], gv, yacc[1][cs]);
                }
                __builtin_amdgcn_s_setprio(0);
            }

            if (jt < 14) { asm volatile("s_waitcnt vmcnt(4)" ::: "memory"); }
            else         { asm volatile("s_waitcnt vmcnt(0)" ::: "memory"); }
            __builtin_amdgcn_s_barrier();
        }

        // cross-pair reduction: js=1 partials -> js=0 waves, per i-set
        float* red = (float*)smem;        // 64 KB overlay (buffers dead)
#pragma unroll
        for (int is = 0; is < 2; is++) {
            __syncthreads();
            if (js == 1) {
#pragma unroll
                for (int cs = 0; cs < 4; cs++)
#pragma unroll
                    for (int rq = 0; rq < 4; rq++) {
                        f32x4 v;
                        v[0] = yacc[is][cs][rq * 4 + 0];
                        v[1] = yacc[is][cs][rq * 4 + 1];
                        v[2] = yacc[is][cs][rq * 4 + 2];
                        v[3] = yacc[is][cs][rq * 4 + 3];
                        *reinterpret_cast<f32x4*>(&red[((iw * 4 + cs) * 4 + rq) * 256 + l * 4]) = v;
                    }
            }
            __syncthreads();
            if (js == 0) {
#pragma unroll
                for (int cs = 0; cs < 4; cs++)
#pragma unroll
                    for (int rq = 0; rq < 4; rq++) {
                        f32x4 v = *reinterpret_cast<const f32x4*>(
                            &red[((iw * 4 + cs) * 4 + rq) * 256 + l * 4]);
                        yacc[is][cs][rq * 4 + 0] += v[0];
                        yacc[is][cs][rq * 4 + 1] += v[1];
                        yacc[is][cs][rq * 4 + 2] += v[2];
                        yacc[is][cs][rq * 4 + 3] += v[3];
                    }
            }
        }
        __syncthreads();

        // epilogue (js=0 waves): transpose via per-wave LDS, store yP
        if (js == 0) {
            f16* yw = (f16*)smem + iw * (32 * 136);
#pragma unroll
            for (int is = 0; is < 2; is++) {
#pragma unroll
                for (int cs = 0; cs < 4; cs++)
#pragma unroll
                    for (int r = 0; r < 16; r++)
                        yw[((r & 3) + 8 * (r >> 2) + 4 * hi) * 136 + cs * 32 + l31] =
                            (f16)yacc[is][cs][r];
                f16* yo = yP + (size_t)jq * PSZ + ((size_t)bb * N_ + i0 + iw * 64 + is * 32) * CI;
                __builtin_amdgcn_s_waitcnt(0);   // lgkm: yw writes visible to own wave
#pragma unroll
                for (int rr = 0; rr < 8; rr++) {
                    int chunk = rr * 64 + l;
                    int il = chunk >> 4, u = chunk & 15;
                    *reinterpret_cast<f16x8*>(yo + il * CI + u * 8) =
                        *reinterpret_cast<const f16x8*>(&yw[il * 136 + u * 8]);
                }
                __builtin_amdgcn_s_waitcnt(0);   // drain reads before is=1 overwrites yw
            }
        }
    }
    __threadfence();
    grid.sync();

    // ================= P4: wz — 2 units/block (R18 mapping) ================
    {
        const f16* wzc = wcvt + 3 * 32768;
        int id = blk * 2 + sub;            // 0..511
        int nb = id & 127, bb = id >> 7;
        int w4 = tt >> 6, l16 = tt & 15, q = (tt & 63) >> 4;
        int o0 = w4 * 64, n0 = nb * 32;
        f32x4 acc[4][2] = {};              // [os][nt]
#pragma unroll
        for (int kk = 0; kk < 4; kk++) {
            f16x8 bv[2];
#pragma unroll
            for (int nt = 0; nt < 2; nt++) {
                size_t yi = ((size_t)bb * N_ + n0 + nt * 16 + l16) * CI + kk * 32 + q * 8;
                f16x8 b0 = *reinterpret_cast<const f16x8*>(yP + yi);
                f16x8 b1 = *reinterpret_cast<const f16x8*>(yP + PSZ + yi);
                f16x8 b2 = *reinterpret_cast<const f16x8*>(yP + 2 * PSZ + yi);
                f16x8 b3 = *reinterpret_cast<const f16x8*>(yP + 3 * PSZ + yi);
                bv[nt] = (b0 + b1) + (b2 + b3);
            }
#pragma unroll
            for (int os = 0; os < 4; os++) {
                f16x8 av = *reinterpret_cast<const f16x8*>(
                    wzc + (o0 + os * 16 + l16) * CI + kk * 32 + q * 8);
#pragma unroll
                for (int nt = 0; nt < 2; nt++)
                    acc[os][nt] = MFMA(av, bv[nt], acc[os][nt]);
            }
        }
#pragma unroll
        for (int os = 0; os < 4; os++)
#pragma unroll
        for (int r = 0; r < 4; r++) {
            int o = o0 + os * 16 + q * 4 + r;
            float bias = zb[o];
            float sr = 0.f, qr = 0.f;
#pragma unroll
            for (int nt = 0; nt < 2; nt++) {
                float v = acc[os][nt][r] + bias;
                wy[((size_t)bb * C_ + o) * N_ + n0 + nt * 16 + l16] = (f16)v;
                sr += v; qr += v * v;
            }
#pragma unroll
            for (int off = 1; off < 16; off <<= 1) {
                sr += __shfl_xor(sr, off);
                qr += __shfl_xor(qr, off);
            }
            if (l16 == 0) {
                psum[(o * 2 + 0) * 512 + id] = sr;
                psum[(o * 2 + 1) * 512 + id] = qr;
            }
        }
    }
    __threadfence();
    grid.sync();

    // ================= P5: final — 2 parallel x 4 sequential ===============
    {
        float* s8 = (float*)smem + sub * 8;
        int w4 = tt >> 6;
        for (int rep = 0; rep < 4; rep++) {
            int vid = blk * 8 + sub * 4 + rep;   // 0..2047
            int p = vid * 256 + tt;              // group of 8 elems
            int c = (p >> 9) & 255;              // uniform within 256-thr unit
            float sr = psum[(c * 2 + 0) * 512 + tt] + psum[(c * 2 + 0) * 512 + 256 + tt];
            float qr = psum[(c * 2 + 1) * 512 + tt] + psum[(c * 2 + 1) * 512 + 256 + tt];
#pragma unroll
            for (int off = 1; off < 64; off <<= 1) {
                sr += __shfl_xor(sr, off);
                qr += __shfl_xor(qr, off);
            }
            if ((tt & 63) == 0) { s8[w4 * 2] = sr; s8[w4 * 2 + 1] = qr; }
            __syncthreads();
            float ssum = s8[0] + s8[2] + s8[4] + s8[6];
            float ssq  = s8[1] + s8[3] + s8[5] + s8[7];
            __syncthreads();                     // s8 reusable next rep

            const float inv = 1.0f / 16384.0f;
            float mean = ssum * inv;
            float var = ssq * inv - mean * mean;
            float s = gamma[c] * rsqrtf(var + 1e-5f);
            float h = beta[c] - mean * s;
            f16x8 wv = reinterpret_cast<const f16x8*>(wy)[p];
            float4 x0 = reinterpret_cast<const float4*>(x)[2 * p];
            float4 x1 = reinterpret_cast<const float4*>(x)[2 * p + 1];
            float4 o0, o1;
            o0.x = (float)wv[0] * s + h + x0.x;
            o0.y = (float)wv[1] * s + h + x0.y;
            o0.z = (float)wv[2] * s + h + x0.z;
            o0.w = (float)wv[3] * s + h + x0.w;
            o1.x = (float)wv[4] * s + h + x1.x;
            o1.y = (float)wv[5] * s + h + x1.y;
            o1.z = (float)wv[6] * s + h + x1.z;
            o1.w = (float)wv[7] * s + h + x1.w;
            reinterpret_cast<float4*>(out)[2 * p] = o0;
            reinterpret_cast<float4*>(out)[2 * p + 1] = o1;
        }
    }
}

extern "C" void kernel_launch(void* const* d_in, const int* in_sizes, int n_in,
                              void* d_out, int out_size, void* d_ws, size_t ws_size,
                              hipStream_t stream) {
    const float* x     = (const float*)d_in[0];
    const float* gw    = (const float*)d_in[1];
    const float* gb    = (const float*)d_in[2];
    const float* tw    = (const float*)d_in[3];
    const float* tbv   = (const float*)d_in[4];
    const float* pw    = (const float*)d_in[5];
    const float* pb    = (const float*)d_in[6];
    const float* zw    = (const float*)d_in[7];
    const float* zb    = (const float*)d_in[8];
    const float* gamma = (const float*)d_in[9];
    const float* beta  = (const float*)d_in[10];
    float* outp = (float*)d_out;
    char* wsp   = (char*)d_ws;

    void* kargs[] = {
        (void*)&x, (void*)&gw, (void*)&gb, (void*)&tw, (void*)&tbv,
        (void*)&pw, (void*)&pb, (void*)&zw, (void*)&zb, (void*)&gamma,
        (void*)&beta, (void*)&outp, (void*)&wsp };
    hipLaunchCooperativeKernel(k_mono, dim3(256), dim3(512), kargs, 0, stream);
}

// Round 11
// 184.147 us; speedup vs baseline: 3.2005x; 3.2005x over previous
//
#include <hip/hip_runtime.h>

// NonLocalBlock: B=4, C=256, Ci=128, H=W=64, N=4096.
// R20 = R16 verbatim (best measured: 185.1us). R19 post-mortem: cooperative
// mono-kernel catastrophically regressed (589us; grid.sync ~60us each on
// 8-XCD MI355X — cross-XCD fence + atomic spin — vs ~5us stream dispatch
// boundaries). R17 (inline weight cvt) +15.4, R18 (k_wz split) +2.9 also
// refuted. This restores the measured optimum: k_init + k_proj (3-proj
// fused, log2e folded) + k_cols (32x32 swapped, lane-local j) + k_attn
// (counted-vmcnt 3-buffer, in-reg softmax via cvt_pkrtz+permlane32_swap,
// colmerge folded into prologue) + k_wz (grid 256) + k_final (k_red folded).

#define B_  4
#define C_  256
#define CI  128
#define N_  4096
#define NB  (B_*N_)     // 16384
#define ISPLIT 16
#define MB_ (1u<<20)
#define LOG2E 1.442695041f

typedef _Float16 f16;
typedef f16   f16x8 __attribute__((ext_vector_type(8)));
typedef f16   f16x4 __attribute__((ext_vector_type(4)));
typedef float f32x4 __attribute__((ext_vector_type(4)));
typedef float f32x16 __attribute__((ext_vector_type(16)));
typedef unsigned u32x2 __attribute__((ext_vector_type(2)));
typedef unsigned u32x4v __attribute__((ext_vector_type(4)));

#define MFMA(a,b,c)   __builtin_amdgcn_mfma_f32_16x16x32_f16(a,b,c,0,0,0)
#define MFMA32(a,b,c) __builtin_amdgcn_mfma_f32_32x32x16_f16(a,b,c,0,0,0)

// async global->LDS, 16B per lane; LDS dest = wave-uniform base + lane*16
#define GLD16(g, lp) __builtin_amdgcn_global_load_lds( \
    (const __attribute__((address_space(1))) void*)(g), \
    (__attribute__((address_space(3))) void*)(lp), 16, 0, 0)

// ---- workspace byte offsets (~30 MB) ----
#define OFF_THETA  0                 // f16 [B][N][CI]  4 MB (pre-scaled by log2e)
#define OFF_PHI    (4u*MB_)          // f16 [B][N][CI]  4 MB
#define OFF_G      (8u*MB_)          // f16 [B][CI][N]  4 MB
#define OFF_YP     (12u*MB_)         // f16 [4][B][N][CI]  16 MB (j-quarter partials)
#define OFF_WY     0                 // f16 [B][C][N] 8 MB — overlays theta+phi (dead by k_wz)
#define OFF_PS     (28u*MB_)                  // f32 [ISPLIT][NB]  1 MB
#define OFF_PSUM   (OFF_PS + ISPLIT*NB*4)     // f32 [256][2][256]  512 KB
#define OFF_WCVT   (OFF_PSUM + 524288)        // f16 weights g,t,p,z  256 KB
#define PSZ ((size_t)B_*N_*CI)

// ---------------- init: weight cvt f32->f16 ----------------
__global__ void k_init(const float* gw, const float* tw, const float* pw,
                       const float* zw, f16* wcvt) {
    int i = blockIdx.x * 256 + threadIdx.x;          // 0..131071
    const float* s;
    int which = i >> 15;
    if (which == 0) s = gw; else if (which == 1) s = tw;
    else if (which == 2) s = pw; else s = zw;
    wcvt[i] = (f16)s[i & 32767];
}

// ---------------- fused 1x1-conv projections (all 3, one x read) ----------------
__global__ __launch_bounds__(256) void k_proj(
        const float* __restrict__ x, const f16* __restrict__ wcvt,
        const float* __restrict__ gb, const float* __restrict__ tb,
        const float* __restrict__ pb,
        f16* __restrict__ thetaT, f16* __restrict__ phiT, f16* __restrict__ gC) {
    __shared__ __align__(16) f16 xT[32 * 264];       // [n][c], stride 264
    int bb = blockIdx.x >> 7;
    int n0 = (blockIdx.x & 127) * 32;
    int t = threadIdx.x;

    const float* xb = x + (size_t)bb * C_ * N_;
    for (int rep = 0; rep < 8; rep++) {
        int lin = rep * 256 + t;
        int c = lin >> 3, np = (lin & 7) * 4;
        float4 v = *reinterpret_cast<const float4*>(xb + c * N_ + n0 + np);
        xT[(np + 0) * 264 + c] = (f16)v.x;
        xT[(np + 1) * 264 + c] = (f16)v.y;
        xT[(np + 2) * 264 + c] = (f16)v.z;
        xT[(np + 3) * 264 + c] = (f16)v.w;
    }
    __syncthreads();

    int w = t >> 6, l16 = t & 15, q = (t & 63) >> 4;
    int ci0 = w * 32;
    for (int proj = 0; proj < 3; proj++) {
        const f16* W0 = wcvt + proj * 32768;         // [128][256] f16 row-major
        f32x4 acc[2][2] = {};
        for (int kk = 0; kk < 8; kk++) {
            f16x8 a0 = *reinterpret_cast<const f16x8*>(W0 + (ci0 + l16) * 256 + kk * 32 + q * 8);
            f16x8 a1 = *reinterpret_cast<const f16x8*>(W0 + (ci0 + 16 + l16) * 256 + kk * 32 + q * 8);
#pragma unroll
            for (int nt = 0; nt < 2; nt++) {
                f16x8 bv = *reinterpret_cast<const f16x8*>(&xT[(nt * 16 + l16) * 264 + kk * 32 + q * 8]);
                acc[0][nt] = MFMA(a0, bv, acc[0][nt]);
                acc[1][nt] = MFMA(a1, bv, acc[1][nt]);
            }
        }
        const float* bias = (proj == 0) ? gb : (proj == 1) ? tb : pb;
        float scl = (proj == 1) ? LOG2E : 1.0f;      // fold ln2 into theta
#pragma unroll
        for (int a = 0; a < 2; a++) {
#pragma unroll
            for (int nt = 0; nt < 2; nt++) {
                int n = n0 + nt * 16 + l16;
                int cib = ci0 + a * 16 + q * 4;
                if (proj == 0) {
#pragma unroll
                    for (int r = 0; r < 4; r++)
                        gC[((size_t)bb * CI + cib + r) * N_ + n] = (f16)(acc[a][nt][r] + bias[cib + r]);
                } else {
                    f16x4 v4;
#pragma unroll
                    for (int r = 0; r < 4; r++)
                        v4[r] = (f16)((acc[a][nt][r] + bias[cib + r]) * scl);
                    f16* dst = (proj == 1 ? thetaT : phiT) + ((size_t)bb * N_ + n) * CI + cib;
                    *reinterpret_cast<f16x4*>(dst) = v4;
                }
            }
        }
    }
}

// ---------------- pass 2: column exp-sums (32x32 swapped, lane-local j) ------
// grid 2048 = bb(4) x jb(32) x isp(16); i-slice 256 = 4 staged tiles of 64.
__global__ __launch_bounds__(256, 4) void k_cols(
        const f16* __restrict__ thetaT, const f16* __restrict__ phiT,
        float* __restrict__ ps) {
    __shared__ __align__(16) f16 thS[2][64 * 128];
    int id = blockIdx.x;                 // 2048
    int isp = id & 15, jb = (id >> 4) & 31, bb = id >> 9;
    int t = threadIdx.x, w = t >> 6, l = t & 63;
    int l31 = l & 31, hi = l >> 5;
    int jw = jb * 128 + w * 32 + l31;    // this lane's j column

    // phi B-frags: B[k][n=j], lane n=l31, k = kk*16 + hi*8 + e
    f16x8 pf[8];
    const f16* pb = phiT + ((size_t)bb * N_ + jw) * CI + hi * 8;
#pragma unroll
    for (int kk = 0; kk < 8; kk++)
        pf[kk] = *reinterpret_cast<const f16x8*>(pb + kk * 16);

    const f16* thB = thetaT + ((size_t)bb * N_ + isp * 256) * CI;
    auto stage = [&](int bf, int it0) {
#pragma unroll
        for (int r = 0; r < 4; r++) {
            int p = r * 256 + w * 64 + l;
            int pi = p >> 4, pu = (p & 15) ^ (pi & 15);
            const char* ga = (const char*)(thB + (size_t)(it0 + pi) * CI) + pu * 16;
            GLD16(ga, &thS[bf][(r * 256 + w * 64) * 8]);
        }
    };

    float s = 0.f;
    stage(0, 0);
    __syncthreads();
    for (int it = 0; it < 4; it++) {
        int bf = it & 1;
        if (it + 1 < 4) stage(bf ^ 1, (it + 1) * 64);
#pragma unroll
        for (int it2 = 0; it2 < 2; it2++) {
            f16x8 av[8];
#pragma unroll
            for (int kk = 0; kk < 8; kk++)
                av[kk] = *reinterpret_cast<const f16x8*>(
                    &thS[bf][(it2 * 32 + l31) * 128 + (((kk * 2 + hi) ^ (l31 & 15)) * 8)]);
            f32x16 f = {};
            __builtin_amdgcn_s_setprio(1);
#pragma unroll
            for (int kk = 0; kk < 8; kk++)
                f = MFMA32(av[kk], pf[kk], f);
            __builtin_amdgcn_s_setprio(0);
#pragma unroll
            for (int r = 0; r < 16; r++)
                s += __builtin_amdgcn_exp2f(f[r]);
        }
        __syncthreads();
    }
    s += __shfl_xor(s, 32);
    if (hi == 0)
        ps[isp * NB + bb * N_ + jw] = s;
}

// ---------------- pass 3: y = softmax(f) @ g  (counted-vmcnt 3-buffer) ------
// grid 256 = jq(4) x bb(4) x ib(16); block = 512 threads (8 waves) on 256 i.
// Wave w: js = w>>2 (32-j half), iw = w&3 (64-i block, 2 i-sets of 32).
// Prologue folds colmerge: mdL[j] = -log2(sum_isp ps) computed in-block.
// Schedule: stage(t+2) -> compute(t) -> s_waitcnt vmcnt(4) -> raw s_barrier.
__global__ __launch_bounds__(512, 2) void k_attn(
        const f16* __restrict__ thetaT, const f16* __restrict__ phiT,
        const f16* __restrict__ gC, const float* __restrict__ ps,
        f16* __restrict__ yP) {
    __shared__ __align__(16) char smem[102400];      // 3x(16+16) KB tiles + 4 KB md
    f16 (*phiS)[64 * 128] = (f16(*)[64 * 128])smem;            // 3 x 16 KB [j][ci]
    f16 (*gS)[128 * 64]   = (f16(*)[128 * 64])(smem + 49152);  // 3 x 16 KB [ci][j]
    float* mdL = (float*)(smem + 98304);                       // [1024] -log2 D

    int jq = blockIdx.x & 3;
    int ib = blockIdx.x >> 2;          // 0..63
    int bb = ib >> 4;
    int i0 = (ib & 15) * 256;
    int t = threadIdx.x, w = t >> 6, l = t & 63;
    int l31 = l & 31, hi = l >> 5;
    int js = w >> 2, iw = w & 3;
    int jbase = jq * 1024;

    // ---- fold of colmerge: mdL slice from ps (before staging issues) ----
    {
        const float* pp = ps + bb * N_ + jbase;
        float s0 = 0.f, s1 = 0.f;
#pragma unroll
        for (int isp = 0; isp < ISPLIT; isp++) {
            s0 += pp[isp * NB + t];
            s1 += pp[isp * NB + t + 512];
        }
        mdL[t]       = -__log2f(s0);
        mdL[t + 512] = -__log2f(s1);
    }

    // theta B-fragments, 2 i-sets of 32: B[n=i][k]; lane n=l31, k=hi*8+e
    f16x8 ta[2][8];
#pragma unroll
    for (int is = 0; is < 2; is++) {
        const f16* tb = thetaT + ((size_t)bb * N_ + i0 + iw * 64 + is * 32 + l31) * CI + hi * 8;
#pragma unroll
        for (int kk = 0; kk < 8; kk++)
            ta[is][kk] = *reinterpret_cast<const f16x8*>(tb + kk * 16);
    }

    const f16* phiB = phiT + (size_t)bb * N_ * CI;
    const f16* gB   = gC   + (size_t)bb * CI * N_;

    // 512 threads: 2 GLD16 pairs per thread cover 64x128 phi + 128x64 g
    auto stage = [&](int bf, int j0g) {
#pragma unroll
        for (int r = 0; r < 2; r++) {
            int p = r * 512 + t;
            int ub = (r * 512 + w * 64) * 8;          // wave-uniform LDS base (f16)
            int pj = p >> 4, pu = (p & 15) ^ (pj & 15);
            const char* ga = (const char*)(phiB + (size_t)(j0g + pj) * CI) + pu * 16;
            GLD16(ga, &phiS[bf][ub]);
            int pc = p >> 3, pu2 = (p & 7) ^ (pc & 7);
            const char* ga2 = (const char*)(gB + (size_t)pc * N_ + j0g) + pu2 * 16;
            GLD16(ga2, &gS[bf][ub]);
        }
    };

    stage(0, jbase);
    stage(1, jbase + 64);
    asm volatile("s_waitcnt vmcnt(4) lgkmcnt(0)" ::: "memory");
    __builtin_amdgcn_s_barrier();

    f32x16 yacc[2][4] = {};              // [iset][cs]: y[i 32][ci = cs*32+l31]
    for (int jt = 0; jt < 16; jt++) {
        int bf = jt % 3;
        if (jt + 2 < 16) stage((jt + 2) % 3, jbase + (jt + 2) * 64);

        // facc init = -log2(D) from LDS (j-dependent only; same for both i-sets)
        f32x16 facc[2];
#pragma unroll
        for (int c = 0; c < 4; c++) {
            f32x4 v = *reinterpret_cast<const f32x4*>(
                &mdL[jt * 64 + js * 32 + c * 8 + hi * 4]);
            facc[0][c * 4 + 0] = v[0]; facc[0][c * 4 + 1] = v[1];
            facc[0][c * 4 + 2] = v[2]; facc[0][c * 4 + 3] = v[3];
            facc[1][c * 4 + 0] = v[0]; facc[1][c * 4 + 1] = v[1];
            facc[1][c * 4 + 2] = v[2]; facc[1][c * 4 + 3] = v[3];
        }

        // QK: each pv read feeds both i-sets
        __builtin_amdgcn_s_setprio(1);
#pragma unroll
        for (int kk = 0; kk < 8; kk++) {
            f16x8 pv = *reinterpret_cast<const f16x8*>(
                &phiS[bf][(js * 32 + l31) * 128 + (((kk * 2 + hi) ^ (l31 & 15)) * 8)]);
            facc[0] = MFMA32(pv, ta[0][kk], facc[0]);
            facc[1] = MFMA32(pv, ta[1][kk], facc[1]);
        }
        __builtin_amdgcn_s_setprio(0);

        // softmax (exp2) + in-register relayout; each gv read feeds both i-sets
#pragma unroll
        for (int ch = 0; ch < 2; ch++) {
            f16x8 wfr[2];
#pragma unroll
            for (int is = 0; is < 2; is++) {
                float e0 = __builtin_amdgcn_exp2f(facc[is][ch * 8 + 0]);
                float e1 = __builtin_amdgcn_exp2f(facc[is][ch * 8 + 1]);
                float e2 = __builtin_amdgcn_exp2f(facc[is][ch * 8 + 2]);
                float e3 = __builtin_amdgcn_exp2f(facc[is][ch * 8 + 3]);
                float e4 = __builtin_amdgcn_exp2f(facc[is][ch * 8 + 4]);
                float e5 = __builtin_amdgcn_exp2f(facc[is][ch * 8 + 5]);
                float e6 = __builtin_amdgcn_exp2f(facc[is][ch * 8 + 6]);
                float e7 = __builtin_amdgcn_exp2f(facc[is][ch * 8 + 7]);
                unsigned p01 = __builtin_bit_cast(unsigned, __builtin_amdgcn_cvt_pkrtz(e0, e1));
                unsigned p23 = __builtin_bit_cast(unsigned, __builtin_amdgcn_cvt_pkrtz(e2, e3));
                unsigned p45 = __builtin_bit_cast(unsigned, __builtin_amdgcn_cvt_pkrtz(e4, e5));
                unsigned p67 = __builtin_bit_cast(unsigned, __builtin_amdgcn_cvt_pkrtz(e6, e7));
                u32x2 s0 = __builtin_amdgcn_permlane32_swap(p01, p45, false, false);
                u32x2 s1 = __builtin_amdgcn_permlane32_swap(p23, p67, false, false);
                u32x4v wu = {s0[0], s1[0], s0[1], s1[1]};
                wfr[is] = __builtin_bit_cast(f16x8, wu);   // A[m=i=l31][k=hi*8+e]
            }
            int jc = js * 2 + ch;                          // 16-j chunk index
            __builtin_amdgcn_s_setprio(1);
#pragma unroll
            for (int cs = 0; cs < 4; cs++) {
                f16x8 gv = *reinterpret_cast<const f16x8*>(
                    &gS[bf][(cs * 32 + l31) * 64 + (((jc * 2 + hi) ^ (l31 & 7)) * 8)]);
                yacc[0][cs] = MFMA32(wfr[0], gv, yacc[0][cs]);
                yacc[1][cs] = MFMA32(wfr[1], gv, yacc[1][cs]);
            }
            __builtin_amdgcn_s_setprio(0);
        }

        // counted wait: keep tile t+2 in flight (4 loads/wave); drain at tail
        if (jt < 14) { asm volatile("s_waitcnt vmcnt(4)" ::: "memory"); }
        else         { asm volatile("s_waitcnt vmcnt(0)" ::: "memory"); }
        __builtin_amdgcn_s_barrier();
    }

    // ---- cross-pair reduction: js=1 partials -> js=0 waves, per i-set ----
    float* red = (float*)smem;            // 64 KB overlay (buffers dead)
#pragma unroll
    for (int is = 0; is < 2; is++) {
        __syncthreads();
        if (js == 1) {
#pragma unroll
            for (int cs = 0; cs < 4; cs++)
#pragma unroll
                for (int rq = 0; rq < 4; rq++) {
                    f32x4 v;
                    v[0] = yacc[is][cs][rq * 4 + 0];
                    v[1] = yacc[is][cs][rq * 4 + 1];
                    v[2] = yacc[is][cs][rq * 4 + 2];
                    v[3] = yacc[is][cs][rq * 4 + 3];
                    *reinterpret_cast<f32x4*>(&red[((iw * 4 + cs) * 4 + rq) * 256 + l * 4]) = v;
                }
        }
        __syncthreads();
        if (js == 0) {
#pragma unroll
            for (int cs = 0; cs < 4; cs++)
#pragma unroll
                for (int rq = 0; rq < 4; rq++) {
                    f32x4 v = *reinterpret_cast<const f32x4*>(
                        &red[((iw * 4 + cs) * 4 + rq) * 256 + l * 4]);
                    yacc[is][cs][rq * 4 + 0] += v[0];
                    yacc[is][cs][rq * 4 + 1] += v[1];
                    yacc[is][cs][rq * 4 + 2] += v[2];
                    yacc[is][cs][rq * 4 + 3] += v[3];
                }
        }
    }
    __syncthreads();

    // ---- epilogue (js=0 waves): transpose via per-wave LDS, store yP ----
    if (js == 0) {
        f16* yw = (f16*)smem + iw * (32 * 136);
#pragma unroll
        for (int is = 0; is < 2; is++) {
#pragma unroll
            for (int cs = 0; cs < 4; cs++)
#pragma unroll
                for (int r = 0; r < 16; r++)
                    yw[((r & 3) + 8 * (r >> 2) + 4 * hi) * 136 + cs * 32 + l31] =
                        (f16)yacc[is][cs][r];
            f16* yo = yP + (size_t)jq * PSZ + ((size_t)bb * N_ + i0 + iw * 64 + is * 32) * CI;
            __builtin_amdgcn_s_waitcnt(0);   // lgkm: yw writes visible to own wave
#pragma unroll
            for (int rr = 0; rr < 8; rr++) {
                int chunk = rr * 64 + l;
                int il = chunk >> 4, u = chunk & 15;
                *reinterpret_cast<f16x8*>(yo + il * CI + u * 8) =
                    *reinterpret_cast<const f16x8*>(&yw[il * 136 + u * 8]);
            }
            __builtin_amdgcn_s_waitcnt(0);   // drain reads before is=1 overwrites yw
        }
    }
}

// ---------------- pass 4: w_y = wz @ (sum of y partials) + b ----------------
// grid 256: block = bb(4) x nb(64 n-tiles of 64); reads its yP slice ONCE,
// computes all 256 output channels; per-block channel partials -> psum.
__global__ __launch_bounds__(256) void k_wz(
        const f16* __restrict__ wzc, const f16* __restrict__ yP,
        const float* __restrict__ zb, f16* __restrict__ wy,
        float* __restrict__ psum) {
    int id = blockIdx.x;                  // 256
    int nb = id & 63, bb = id >> 6;
    int t = threadIdx.x, w = t >> 6, l16 = t & 15, q = (t & 63) >> 4;
    int o0 = w * 64, n0 = nb * 64;
    f32x4 acc[4][4] = {};                 // [os][nt]
#pragma unroll
    for (int kk = 0; kk < 4; kk++) {
        f16x8 bv[4];
#pragma unroll
        for (int nt = 0; nt < 4; nt++) {
            size_t yi = ((size_t)bb * N_ + n0 + nt * 16 + l16) * CI + kk * 32 + q * 8;
            f16x8 b0 = *reinterpret_cast<const f16x8*>(yP + yi);
            f16x8 b1 = *reinterpret_cast<const f16x8*>(yP + PSZ + yi);
            f16x8 b2 = *reinterpret_cast<const f16x8*>(yP + 2 * PSZ + yi);
            f16x8 b3 = *reinterpret_cast<const f16x8*>(yP + 3 * PSZ + yi);
            bv[nt] = (b0 + b1) + (b2 + b3);
        }
#pragma unroll
        for (int os = 0; os < 4; os++) {
            f16x8 av = *reinterpret_cast<const f16x8*>(
                wzc + (o0 + os * 16 + l16) * CI + kk * 32 + q * 8);
#pragma unroll
            for (int nt = 0; nt < 4; nt++)
                acc[os][nt] = MFMA(av, bv[nt], acc[os][nt]);
        }
    }
#pragma unroll
    for (int os = 0; os < 4; os++)
#pragma unroll
    for (int r = 0; r < 4; r++) {
        int o = o0 + os * 16 + q * 4 + r;
        float bias = zb[o];
        float sr = 0.f, qr = 0.f;
#pragma unroll
        for (int nt = 0; nt < 4; nt++) {
            float v = acc[os][nt][r] + bias;
            wy[((size_t)bb * C_ + o) * N_ + n0 + nt * 16 + l16] = (f16)v;
            sr += v; qr += v * v;
        }
#pragma unroll
        for (int off = 1; off < 16; off <<= 1) {
            sr += __shfl_xor(sr, off);
            qr += __shfl_xor(qr, off);
        }
        if (l16 == 0) {
            psum[(o * 2 + 0) * 256 + id] = sr;
            psum[(o * 2 + 1) * 256 + id] = qr;
        }
    }
}

// ---------------- pass 5: BN stats (fold of k_red) + BN + residual ----------
__global__ void k_final(const f16* __restrict__ wy, const float* __restrict__ x,
                        const float* __restrict__ psum,
                        const float* __restrict__ gamma, const float* __restrict__ beta,
                        float* __restrict__ out) {
    __shared__ float s8[8];
    int t = threadIdx.x;
    int p = blockIdx.x * 256 + t;                     // 512K groups of 8
    int c = (p >> 9) & 255;                           // block-uniform
    float sr = psum[(c * 2 + 0) * 256 + t];
    float qr = psum[(c * 2 + 1) * 256 + t];
#pragma unroll
    for (int off = 1; off < 64; off <<= 1) {
        sr += __shfl_xor(sr, off);
        qr += __shfl_xor(qr, off);
    }
    int w = t >> 6;
    if ((t & 63) == 0) { s8[w * 2] = sr; s8[w * 2 + 1] = qr; }
    __syncthreads();
    float ssum = s8[0] + s8[2] + s8[4] + s8[6];
    float ssq  = s8[1] + s8[3] + s8[5] + s8[7];

    const float inv = 1.0f / 16384.0f;
    float mean = ssum * inv;
    float var = ssq * inv - mean * mean;
    float s = gamma[c] * rsqrtf(var + 1e-5f);
    float h = beta[c] - mean * s;
    f16x8 wv = reinterpret_cast<const f16x8*>(wy)[p];
    float4 x0 = reinterpret_cast<const float4*>(x)[2 * p];
    float4 x1 = reinterpret_cast<const float4*>(x)[2 * p + 1];
    float4 o0, o1;
    o0.x = (float)wv[0] * s + h + x0.x;
    o0.y = (float)wv[1] * s + h + x0.y;
    o0.z = (float)wv[2] * s + h + x0.z;
    o0.w = (float)wv[3] * s + h + x0.w;
    o1.x = (float)wv[4] * s + h + x1.x;
    o1.y = (float)wv[5] * s + h + x1.y;
    o1.z = (float)wv[6] * s + h + x1.z;
    o1.w = (float)wv[7] * s + h + x1.w;
    reinterpret_cast<float4*>(out)[2 * p] = o0;
    reinterpret_cast<float4*>(out)[2 * p + 1] = o1;
}

extern "C" void kernel_launch(void* const* d_in, const int* in_sizes, int n_in,
                              void* d_out, int out_size, void* d_ws, size_t ws_size,
                              hipStream_t stream) {
    const float* x     = (const float*)d_in[0];
    const float* gw    = (const float*)d_in[1];
    const float* gb    = (const float*)d_in[2];
    const float* tw    = (const float*)d_in[3];
    const float* tbv   = (const float*)d_in[4];
    const float* pw    = (const float*)d_in[5];
    const float* pb    = (const float*)d_in[6];
    const float* zw    = (const float*)d_in[7];
    const float* zb    = (const float*)d_in[8];
    const float* gamma = (const float*)d_in[9];
    const float* beta  = (const float*)d_in[10];

    char* ws = (char*)d_ws;
    f16* thetaT = (f16*)(ws + OFF_THETA);
    f16* phiT   = (f16*)(ws + OFF_PHI);
    f16* gC     = (f16*)(ws + OFF_G);
    f16* yP     = (f16*)(ws + OFF_YP);
    f16* wy     = (f16*)(ws + OFF_WY);
    f16* wcvt   = (f16*)(ws + OFF_WCVT);
    float* ps   = (float*)(ws + OFF_PS);
    float* psum = (float*)(ws + OFF_PSUM);

    k_init<<<512, 256, 0, stream>>>(gw, tw, pw, zw, wcvt);
    k_proj<<<512, 256, 0, stream>>>(x, wcvt, gb, tbv, pb, thetaT, phiT, gC);
    k_cols<<<2048, 256, 0, stream>>>(thetaT, phiT, ps);
    k_attn<<<256, 512, 0, stream>>>(thetaT, phiT, gC, ps, yP);
    k_wz<<<256, 256, 0, stream>>>(wcvt + 3 * 32768, yP, zb, wy, psum);
    k_final<<<2048, 256, 0, stream>>>(wy, x, psum, gamma, beta, (float*)d_out);
}